// Round 3
// baseline (642.725 us; speedup 1.0000x reference)
//
#include <hip/hip_runtime.h>
#include <hip/hip_bf16.h>
#include <cstdint>
#include <cstddef>

#define N_TOK   8192
#define D_MODEL 1024
#define D_FFN   4096
#define K_TOP   512
#define NHALF   2048   // FFN half-width processed per round

typedef __bf16 bf16_t;
typedef __bf16 bf16x8 __attribute__((ext_vector_type(8)));
typedef __bf16 bf16x4 __attribute__((ext_vector_type(4)));
typedef float  f32x4  __attribute__((ext_vector_type(4)));

// ---------------- aux kernels ----------------

__global__ void cvt_f32_bf16(const float* __restrict__ in, bf16_t* __restrict__ out, int n4) {
  int i = blockIdx.x * blockDim.x + threadIdx.x;
  if (i < n4) {
    const f32x4 v = ((const f32x4*)in)[i];
    bf16x4 o;
    o[0] = (bf16_t)v[0]; o[1] = (bf16_t)v[1]; o[2] = (bf16_t)v[2]; o[3] = (bf16_t)v[3];
    ((bf16x4*)out)[i] = o;
  }
}

// in: [rows][cols] f32  ->  out: [cols][rows] bf16   (B^T layout for GEMM)
__global__ void transpose_cvt(const float* __restrict__ in, bf16_t* __restrict__ out,
                              int rows, int cols) {
  __shared__ float tile[32][33];
  const int tx = threadIdx.x, ty = threadIdx.y;
  const int x = blockIdx.x * 32 + tx;
#pragma unroll
  for (int i = 0; i < 32; i += 8) {
    int y = blockIdx.y * 32 + ty + i;
    tile[ty + i][tx] = in[(size_t)y * cols + x];
  }
  __syncthreads();
  const int xo = blockIdx.y * 32 + tx;
#pragma unroll
  for (int i = 0; i < 32; i += 8) {
    int yo = blockIdx.x * 32 + ty + i;
    out[(size_t)yo * rows + xo] = (bf16_t)tile[tx][ty + i];
  }
}

// multiplicity counts, packed 8 x 4-bit nibbles per u32 (multiplicity < 16:
// indices ~ Poisson(0.125) per bin -> safe)
__global__ void count_scatter_nib(const int* __restrict__ idx, unsigned int* __restrict__ M) {
  int t = blockIdx.x * blockDim.x + threadIdx.x;
  if (t < N_TOK * K_TOP) {
    int row = t >> 9;  // / K_TOP
    int j = idx[t];
    atomicAdd(&M[(size_t)row * (D_FFN / 8) + (j >> 3)], 1u << ((j & 7) * 4));
  }
}

// ---------------- GEMM common ----------------

#define BK 32

__device__ __forceinline__ void gload_lds16(const void* g, void* l) {
#if __has_builtin(__builtin_amdgcn_global_load_lds)
  __builtin_amdgcn_global_load_lds((__attribute__((address_space(1))) void*)(g),
                                   (__attribute__((address_space(3))) void*)(l), 16, 0, 0);
#else
  *(bf16x8*)l = *(const bf16x8*)g;  // fallback: reg staging
#endif
}

// ---------------- GEMM1: gate+up fused, 128x128 tile ----------------
// G,U = A(8192x1024) * {Bg,Bu}^T over one FFN half, fused epilogue
// Z = cnt * silu(G) * U (bf16), Z is [N_TOK][NHALF]
#define BM1 128
#define BN1 128

__global__ __launch_bounds__(256, 3) void gemm_gateup(
    const bf16_t* __restrict__ A,    // [N_TOK][D_MODEL]
    const bf16_t* __restrict__ Bg,   // [D_FFN][D_MODEL]  (w_gate^T)
    const bf16_t* __restrict__ Bu,   // [D_FFN][D_MODEL]  (w_up^T)
    const unsigned int* __restrict__ cnt,  // [N_TOK][D_FFN/8] nibble counts
    bf16_t* __restrict__ Z,          // [N_TOK][NHALF]
    int n_base)                      // 0 or NHALF
{
  __shared__ alignas(16) bf16_t As[BM1 * BK];
  __shared__ alignas(16) bf16_t Bgs[BN1 * BK];
  __shared__ alignas(16) bf16_t Bus[BN1 * BK];

  const int m0 = blockIdx.x * BM1;
  const int n0 = blockIdx.y * BN1;        // local within half
  const int t = threadIdx.x;
  const int lane = t & 63;
  const int w = t >> 6;
  const int wr = w >> 1, wc = w & 1;
  const int l15 = lane & 15;
  const int kk = (lane >> 4) * 8;

  // staging pointers, advanced by BK each K-step (2 rows-of-64 per matrix)
  const int rowi = t >> 2;          // 0..63
  const int coli = (t & 3) * 8;
  const bf16_t* pA  = A  + (size_t)(m0 + rowi) * D_MODEL + coli;
  const bf16_t* pBg = Bg + (size_t)(n_base + n0 + rowi) * D_MODEL + coli;
  const bf16_t* pBu = Bu + (size_t)(n_base + n0 + rowi) * D_MODEL + coli;
  const size_t rstep = (size_t)64 * D_MODEL;

  f32x4 accg[4][4] = {};
  f32x4 accu[4][4] = {};

  for (int k0 = 0; k0 < D_MODEL; k0 += BK) {
    gload_lds16(pA,          As  + t * 8);
    gload_lds16(pA + rstep,  As  + (256 + t) * 8);
    gload_lds16(pBg,         Bgs + t * 8);
    gload_lds16(pBg + rstep, Bgs + (256 + t) * 8);
    gload_lds16(pBu,         Bus + t * 8);
    gload_lds16(pBu + rstep, Bus + (256 + t) * 8);
    pA += BK; pBg += BK; pBu += BK;
    __syncthreads();   // drains vmcnt (global_load_lds) + orders LDS

    bf16x8 af[4], bgf[4], buf[4];
#pragma unroll
    for (int m = 0; m < 4; ++m)
      af[m] = *(const bf16x8*)(As + (wr * 64 + m * 16 + l15) * BK + kk);
#pragma unroll
    for (int n = 0; n < 4; ++n) {
      bgf[n] = *(const bf16x8*)(Bgs + (wc * 64 + n * 16 + l15) * BK + kk);
      buf[n] = *(const bf16x8*)(Bus + (wc * 64 + n * 16 + l15) * BK + kk);
    }
#pragma unroll
    for (int m = 0; m < 4; ++m)
#pragma unroll
      for (int n = 0; n < 4; ++n) {
        accg[m][n] = __builtin_amdgcn_mfma_f32_16x16x32_bf16(af[m], bgf[n], accg[m][n], 0, 0, 0);
        accu[m][n] = __builtin_amdgcn_mfma_f32_16x16x32_bf16(af[m], buf[n], accu[m][n], 0, 0, 0);
      }
    __syncthreads();
  }

  // epilogue: Z = cnt * u * silu(g)   (C/D map: col=lane&15, row=(lane>>4)*4+j)
#pragma unroll
  for (int m = 0; m < 4; ++m) {
#pragma unroll
    for (int n = 0; n < 4; ++n) {
      const int colL = n0 + wc * 64 + n * 16 + l15;   // local col within half
      const int jg = n_base + colL;                   // global FFN index
#pragma unroll
      for (int j = 0; j < 4; ++j) {
        const int row = m0 + wr * 64 + m * 16 + (lane >> 4) * 4 + j;
        float g = accg[m][n][j];
        float u = accu[m][n][j];
        unsigned int cw = cnt[(size_t)row * (D_FFN / 8) + (jg >> 3)];
        float c = (float)((cw >> ((jg & 7) * 4)) & 15u);
        float z = c * u * (g / (1.0f + __expf(-g)));
        Z[(size_t)row * NHALF + colL] = (bf16_t)z;
      }
    }
  }
}

// ---------------- GEMM2: down, 64x128 tile (grid 1024 blocks) ----------------
// out (+)= Z(8192xNHALF) * w_down[k_base:k_base+NHALF, :]
#define BM2 64
#define BN2 128

__global__ __launch_bounds__(256, 4) void gemm_down(
    const bf16_t* __restrict__ A,    // Z [N_TOK][NHALF]
    const bf16_t* __restrict__ B,    // [D_MODEL][D_FFN]  (w_down^T)
    float* __restrict__ C,           // [N_TOK][D_MODEL]
    int k_base, int accum)
{
  __shared__ alignas(16) bf16_t As[BM2 * BK];
  __shared__ alignas(16) bf16_t Bs[BN2 * BK];

  const int m0 = blockIdx.x * BM2;
  const int n0 = blockIdx.y * BN2;
  const int t = threadIdx.x;
  const int lane = t & 63;
  const int w = t >> 6;
  const int wr = w >> 1, wc = w & 1;   // wave tile: 32 rows x 64 cols
  const int l15 = lane & 15;
  const int kk = (lane >> 4) * 8;

  const int rowi = t >> 2;          // 0..63
  const int coli = (t & 3) * 8;
  const bf16_t* pA = A + (size_t)(m0 + rowi) * NHALF + coli;             // 64 rows: 1 slot/thread
  const bf16_t* pB = B + (size_t)(n0 + rowi) * D_FFN + k_base + coli;    // 128 rows: 2 slots/thread
  const size_t rstepB = (size_t)64 * D_FFN;

  f32x4 acc[2][4] = {};

  for (int k0 = 0; k0 < NHALF; k0 += BK) {
    gload_lds16(pA,          As + t * 8);
    gload_lds16(pB,          Bs + t * 8);
    gload_lds16(pB + rstepB, Bs + (256 + t) * 8);
    pA += BK; pB += BK;
    __syncthreads();

    bf16x8 af[2], bf[4];
#pragma unroll
    for (int m = 0; m < 2; ++m)
      af[m] = *(const bf16x8*)(As + (wr * 32 + m * 16 + l15) * BK + kk);
#pragma unroll
    for (int n = 0; n < 4; ++n)
      bf[n] = *(const bf16x8*)(Bs + (wc * 64 + n * 16 + l15) * BK + kk);
#pragma unroll
    for (int m = 0; m < 2; ++m)
#pragma unroll
      for (int n = 0; n < 4; ++n)
        acc[m][n] = __builtin_amdgcn_mfma_f32_16x16x32_bf16(af[m], bf[n], acc[m][n], 0, 0, 0);
    __syncthreads();
  }

#pragma unroll
  for (int m = 0; m < 2; ++m) {
#pragma unroll
    for (int n = 0; n < 4; ++n) {
      const int col = n0 + wc * 64 + n * 16 + l15;
#pragma unroll
      for (int j = 0; j < 4; ++j) {
        const int row = m0 + wr * 32 + m * 16 + (lane >> 4) * 4 + j;
        const size_t off = (size_t)row * D_MODEL + col;
        float prev = accum ? C[off] : 0.0f;
        C[off] = prev + acc[m][n][j];
      }
    }
  }
}

// ---------------- launch ----------------

extern "C" void kernel_launch(void* const* d_in, const int* in_sizes, int n_in,
                              void* d_out, int out_size, void* d_ws, size_t ws_size,
                              hipStream_t stream) {
  const float* x  = (const float*)d_in[0];
  const int*   idx = (const int*)d_in[1];
  const float* wg = (const float*)d_in[2];
  const float* wu = (const float*)d_in[3];
  const float* wd = (const float*)d_in[4];
  float* out = (float*)d_out;

  char* ws = (char*)d_ws;
  const size_t SZ_XB  = (size_t)N_TOK * D_MODEL * 2;   // 16 MB
  const size_t SZ_W   = (size_t)D_MODEL * D_FFN * 2;   //  8 MB each
  const size_t SZ_CNT = (size_t)N_TOK * D_FFN / 2;     // 16 MB (4-bit counts)
  bf16_t* xb  = (bf16_t*)(ws);
  bf16_t* wgT = (bf16_t*)(ws + SZ_XB);
  bf16_t* wuT = (bf16_t*)(ws + SZ_XB + SZ_W);
  bf16_t* wdT = (bf16_t*)(ws + SZ_XB + 2 * SZ_W);
  unsigned int* cnt = (unsigned int*)(ws + SZ_XB + 3 * SZ_W);
  bf16_t* Z   = (bf16_t*)(ws + SZ_XB + 3 * SZ_W + SZ_CNT);  // [N_TOK][NHALF]
  // total ws use: 16 + 24 + 16 + 32 = 88 MB

  hipMemsetAsync(cnt, 0, SZ_CNT, stream);

  cvt_f32_bf16<<<(N_TOK * D_MODEL / 4 + 255) / 256, 256, 0, stream>>>(x, xb, N_TOK * D_MODEL / 4);
  transpose_cvt<<<dim3(D_FFN / 32, D_MODEL / 32), dim3(32, 8), 0, stream>>>(wg, wgT, D_MODEL, D_FFN);
  transpose_cvt<<<dim3(D_FFN / 32, D_MODEL / 32), dim3(32, 8), 0, stream>>>(wu, wuT, D_MODEL, D_FFN);
  transpose_cvt<<<dim3(D_MODEL / 32, D_FFN / 32), dim3(32, 8), 0, stream>>>(wd, wdT, D_FFN, D_MODEL);
  count_scatter_nib<<<(N_TOK * K_TOP + 255) / 256, 256, 0, stream>>>(idx, cnt);

  // two FFN halves, Z buffer reused (stream-ordered)
  gemm_gateup<<<dim3(N_TOK / BM1, NHALF / BN1), 256, 0, stream>>>(xb, wgT, wuT, cnt, Z, 0);
  gemm_down<<<dim3(N_TOK / BM2, D_MODEL / BN2), 256, 0, stream>>>(Z, wdT, out, 0, 0);
  gemm_gateup<<<dim3(N_TOK / BM1, NHALF / BN1), 256, 0, stream>>>(xb, wgT, wuT, cnt, Z, NHALF);
  gemm_down<<<dim3(N_TOK / BM2, D_MODEL / BN2), 256, 0, stream>>>(Z, wdT, out, NHALF, 1);
}

// Round 4
// 398.966 us; speedup vs baseline: 1.6110x; 1.6110x over previous
//
#include <hip/hip_runtime.h>
#include <hip/hip_bf16.h>
#include <cstdint>
#include <cstddef>

#define N_TOK   8192
#define D_MODEL 1024
#define D_FFN   4096
#define K_TOP   512
#define NHALF   2048   // FFN half-width processed per round

typedef __bf16 bf16_t;
typedef __bf16 bf16x8 __attribute__((ext_vector_type(8)));
typedef __bf16 bf16x4 __attribute__((ext_vector_type(4)));
typedef float  f32x4  __attribute__((ext_vector_type(4)));

// ---------------- aux kernels ----------------

__global__ void cvt_f32_bf16(const float* __restrict__ in, bf16_t* __restrict__ out, int n4) {
  int i = blockIdx.x * blockDim.x + threadIdx.x;
  if (i < n4) {
    const f32x4 v = ((const f32x4*)in)[i];
    bf16x4 o;
    o[0] = (bf16_t)v[0]; o[1] = (bf16_t)v[1]; o[2] = (bf16_t)v[2]; o[3] = (bf16_t)v[3];
    ((bf16x4*)out)[i] = o;
  }
}

// in: [rows][cols] f32  ->  out: [cols][rows] bf16   (B^T layout for GEMM)
__global__ void transpose_cvt(const float* __restrict__ in, bf16_t* __restrict__ out,
                              int rows, int cols) {
  __shared__ float tile[32][33];
  const int tx = threadIdx.x, ty = threadIdx.y;
  const int x = blockIdx.x * 32 + tx;
#pragma unroll
  for (int i = 0; i < 32; i += 8) {
    int y = blockIdx.y * 32 + ty + i;
    tile[ty + i][tx] = in[(size_t)y * cols + x];
  }
  __syncthreads();
  const int xo = blockIdx.y * 32 + tx;
#pragma unroll
  for (int i = 0; i < 32; i += 8) {
    int yo = blockIdx.x * 32 + ty + i;
    out[(size_t)yo * rows + xo] = (bf16_t)tile[tx][ty + i];
  }
}

// multiplicity counts, packed 8 x 4-bit nibbles per u32 (multiplicity < 16:
// indices ~ Poisson(0.125) per bin -> safe)
__global__ void count_scatter_nib(const int* __restrict__ idx, unsigned int* __restrict__ M) {
  int t = blockIdx.x * blockDim.x + threadIdx.x;
  if (t < N_TOK * K_TOP) {
    int row = t >> 9;  // / K_TOP
    int j = idx[t];
    atomicAdd(&M[(size_t)row * (D_FFN / 8) + (j >> 3)], 1u << ((j & 7) * 4));
  }
}

// ---------------- GEMM common ----------------

#define BK 32

__device__ __forceinline__ void gload_lds16(const void* g, void* l) {
#if __has_builtin(__builtin_amdgcn_global_load_lds)
  __builtin_amdgcn_global_load_lds((__attribute__((address_space(1))) void*)(g),
                                   (__attribute__((address_space(3))) void*)(l), 16, 0, 0);
#else
  *(bf16x8*)l = *(const bf16x8*)g;  // fallback: reg staging
#endif
}

// ---------------- GEMM1: gate+up fused, 128x128 tile, 512 thr / 8 waves ----
// Wave-tile 64x32 (wr=w>>2, wc=w&3): per-thread acc = 2*(4x2) f32x4 = 64 VGPR
// (dual-acc floor is 128 VGPR at 4x4 — that config can't reach 3 waves/SIMD;
//  DO NOT cap launch bounds below acc floor: R3 spilled at cap=170, 84 VGPR,
//  520 MB scratch writes, MfmaUtil 1%.)
#define BM1 128
#define BN1 128

__global__ __launch_bounds__(512, 4) void gemm_gateup(
    const bf16_t* __restrict__ A,    // [N_TOK][D_MODEL]
    const bf16_t* __restrict__ Bg,   // [D_FFN][D_MODEL]  (w_gate^T)
    const bf16_t* __restrict__ Bu,   // [D_FFN][D_MODEL]  (w_up^T)
    const unsigned int* __restrict__ cnt,  // [N_TOK][D_FFN/8] nibble counts
    bf16_t* __restrict__ Z,          // [N_TOK][NHALF]
    int n_base)                      // 0 or NHALF
{
  __shared__ alignas(16) bf16_t As[BM1 * BK];
  __shared__ alignas(16) bf16_t Bgs[BN1 * BK];
  __shared__ alignas(16) bf16_t Bus[BN1 * BK];

  const int m0 = blockIdx.x * BM1;
  const int n0 = blockIdx.y * BN1;        // local within half
  const int t = threadIdx.x;
  const int lane = t & 63;
  const int w = t >> 6;                   // 0..7
  const int wr = w >> 2, wc = w & 3;      // 2 x 4 wave grid; wave-tile 64x32
  const int l15 = lane & 15;
  const int kk = (lane >> 4) * 8;

  // staging: 512 threads, 1 x 16B slot per matrix per thread per K-step
  const int rowi = t >> 2;          // 0..127
  const int coli = (t & 3) * 8;
  const bf16_t* pA  = A  + (size_t)(m0 + rowi) * D_MODEL + coli;
  const bf16_t* pBg = Bg + (size_t)(n_base + n0 + rowi) * D_MODEL + coli;
  const bf16_t* pBu = Bu + (size_t)(n_base + n0 + rowi) * D_MODEL + coli;

  f32x4 accg[4][2] = {};
  f32x4 accu[4][2] = {};

  for (int k0 = 0; k0 < D_MODEL; k0 += BK) {
    gload_lds16(pA,  As  + t * 8);
    gload_lds16(pBg, Bgs + t * 8);
    gload_lds16(pBu, Bus + t * 8);
    pA += BK; pBg += BK; pBu += BK;
    __syncthreads();   // drains vmcnt (global_load_lds) + orders LDS

    bf16x8 af[4], bgf[2], buf[2];
#pragma unroll
    for (int m = 0; m < 4; ++m)
      af[m] = *(const bf16x8*)(As + (wr * 64 + m * 16 + l15) * BK + kk);
#pragma unroll
    for (int n = 0; n < 2; ++n) {
      bgf[n] = *(const bf16x8*)(Bgs + (wc * 32 + n * 16 + l15) * BK + kk);
      buf[n] = *(const bf16x8*)(Bus + (wc * 32 + n * 16 + l15) * BK + kk);
    }
#pragma unroll
    for (int m = 0; m < 4; ++m)
#pragma unroll
      for (int n = 0; n < 2; ++n) {
        accg[m][n] = __builtin_amdgcn_mfma_f32_16x16x32_bf16(af[m], bgf[n], accg[m][n], 0, 0, 0);
        accu[m][n] = __builtin_amdgcn_mfma_f32_16x16x32_bf16(af[m], buf[n], accu[m][n], 0, 0, 0);
      }
    __syncthreads();
  }

  // epilogue: Z = cnt * u * silu(g)   (C/D map: col=lane&15, row=(lane>>4)*4+j)
#pragma unroll
  for (int m = 0; m < 4; ++m) {
#pragma unroll
    for (int n = 0; n < 2; ++n) {
      const int colL = n0 + wc * 32 + n * 16 + l15;   // local col within half
      const int jg = n_base + colL;                   // global FFN index
#pragma unroll
      for (int j = 0; j < 4; ++j) {
        const int row = m0 + wr * 64 + m * 16 + (lane >> 4) * 4 + j;
        float g = accg[m][n][j];
        float u = accu[m][n][j];
        unsigned int cw = cnt[(size_t)row * (D_FFN / 8) + (jg >> 3)];
        float c = (float)((cw >> ((jg & 7) * 4)) & 15u);
        float z = c * u * (g / (1.0f + __expf(-g)));
        Z[(size_t)row * NHALF + colL] = (bf16_t)z;
      }
    }
  }
}

// ---------------- GEMM2: down, 64x128 tile (grid 1024 blocks) ----------------
// out (+)= Z(8192xNHALF) * w_down[k_base:k_base+NHALF, :]
#define BM2 64
#define BN2 128

__global__ __launch_bounds__(256, 4) void gemm_down(
    const bf16_t* __restrict__ A,    // Z [N_TOK][NHALF]
    const bf16_t* __restrict__ B,    // [D_MODEL][D_FFN]  (w_down^T)
    float* __restrict__ C,           // [N_TOK][D_MODEL]
    int k_base, int accum)
{
  __shared__ alignas(16) bf16_t As[BM2 * BK];
  __shared__ alignas(16) bf16_t Bs[BN2 * BK];

  const int m0 = blockIdx.x * BM2;
  const int n0 = blockIdx.y * BN2;
  const int t = threadIdx.x;
  const int lane = t & 63;
  const int w = t >> 6;
  const int wr = w >> 1, wc = w & 1;   // wave tile: 32 rows x 64 cols
  const int l15 = lane & 15;
  const int kk = (lane >> 4) * 8;

  const int rowi = t >> 2;          // 0..63
  const int coli = (t & 3) * 8;
  const bf16_t* pA = A + (size_t)(m0 + rowi) * NHALF + coli;             // 64 rows: 1 slot/thread
  const bf16_t* pB = B + (size_t)(n0 + rowi) * D_FFN + k_base + coli;    // 128 rows: 2 slots/thread
  const size_t rstepB = (size_t)64 * D_FFN;

  f32x4 acc[2][4] = {};

  for (int k0 = 0; k0 < NHALF; k0 += BK) {
    gload_lds16(pA,          As + t * 8);
    gload_lds16(pB,          Bs + t * 8);
    gload_lds16(pB + rstepB, Bs + (256 + t) * 8);
    pA += BK; pB += BK;
    __syncthreads();

    bf16x8 af[2], bf[4];
#pragma unroll
    for (int m = 0; m < 2; ++m)
      af[m] = *(const bf16x8*)(As + (wr * 32 + m * 16 + l15) * BK + kk);
#pragma unroll
    for (int n = 0; n < 4; ++n)
      bf[n] = *(const bf16x8*)(Bs + (wc * 64 + n * 16 + l15) * BK + kk);
#pragma unroll
    for (int m = 0; m < 2; ++m)
#pragma unroll
      for (int n = 0; n < 4; ++n)
        acc[m][n] = __builtin_amdgcn_mfma_f32_16x16x32_bf16(af[m], bf[n], acc[m][n], 0, 0, 0);
    __syncthreads();
  }

#pragma unroll
  for (int m = 0; m < 2; ++m) {
#pragma unroll
    for (int n = 0; n < 4; ++n) {
      const int col = n0 + wc * 64 + n * 16 + l15;
#pragma unroll
      for (int j = 0; j < 4; ++j) {
        const int row = m0 + wr * 32 + m * 16 + (lane >> 4) * 4 + j;
        const size_t off = (size_t)row * D_MODEL + col;
        float prev = accum ? C[off] : 0.0f;
        C[off] = prev + acc[m][n][j];
      }
    }
  }
}

// ---------------- launch ----------------

extern "C" void kernel_launch(void* const* d_in, const int* in_sizes, int n_in,
                              void* d_out, int out_size, void* d_ws, size_t ws_size,
                              hipStream_t stream) {
  const float* x  = (const float*)d_in[0];
  const int*   idx = (const int*)d_in[1];
  const float* wg = (const float*)d_in[2];
  const float* wu = (const float*)d_in[3];
  const float* wd = (const float*)d_in[4];
  float* out = (float*)d_out;

  char* ws = (char*)d_ws;
  const size_t SZ_XB  = (size_t)N_TOK * D_MODEL * 2;   // 16 MB
  const size_t SZ_W   = (size_t)D_MODEL * D_FFN * 2;   //  8 MB each
  const size_t SZ_CNT = (size_t)N_TOK * D_FFN / 2;     // 16 MB (4-bit counts)
  bf16_t* xb  = (bf16_t*)(ws);
  bf16_t* wgT = (bf16_t*)(ws + SZ_XB);
  bf16_t* wuT = (bf16_t*)(ws + SZ_XB + SZ_W);
  bf16_t* wdT = (bf16_t*)(ws + SZ_XB + 2 * SZ_W);
  unsigned int* cnt = (unsigned int*)(ws + SZ_XB + 3 * SZ_W);
  bf16_t* Z   = (bf16_t*)(ws + SZ_XB + 3 * SZ_W + SZ_CNT);  // [N_TOK][NHALF]
  // total ws use: 16 + 24 + 16 + 32 = 88 MB

  hipMemsetAsync(cnt, 0, SZ_CNT, stream);

  cvt_f32_bf16<<<(N_TOK * D_MODEL / 4 + 255) / 256, 256, 0, stream>>>(x, xb, N_TOK * D_MODEL / 4);
  transpose_cvt<<<dim3(D_FFN / 32, D_MODEL / 32), dim3(32, 8), 0, stream>>>(wg, wgT, D_MODEL, D_FFN);
  transpose_cvt<<<dim3(D_FFN / 32, D_MODEL / 32), dim3(32, 8), 0, stream>>>(wu, wuT, D_MODEL, D_FFN);
  transpose_cvt<<<dim3(D_MODEL / 32, D_FFN / 32), dim3(32, 8), 0, stream>>>(wd, wdT, D_FFN, D_MODEL);
  count_scatter_nib<<<(N_TOK * K_TOP + 255) / 256, 256, 0, stream>>>(idx, cnt);

  // two FFN halves, Z buffer reused (stream-ordered)
  gemm_gateup<<<dim3(N_TOK / BM1, NHALF / BN1), 512, 0, stream>>>(xb, wgT, wuT, cnt, Z, 0);
  gemm_down<<<dim3(N_TOK / BM2, D_MODEL / BN2), 256, 0, stream>>>(Z, wdT, out, 0, 0);
  gemm_gateup<<<dim3(N_TOK / BM1, NHALF / BN1), 512, 0, stream>>>(xb, wgT, wuT, cnt, Z, NHALF);
  gemm_down<<<dim3(N_TOK / BM2, D_MODEL / BN2), 256, 0, stream>>>(Z, wdT, out, NHALF, 1);
}

// Round 5
// 310.991 us; speedup vs baseline: 2.0667x; 1.2829x over previous
//
#include <hip/hip_runtime.h>
#include <hip/hip_bf16.h>
#include <cstdint>
#include <cstddef>

#define N_TOK   8192
#define D_MODEL 1024
#define D_FFN   4096
#define K_TOP   512
#define NHALF   2048   // FFN half-width processed per round

typedef __bf16 bf16_t;
typedef __bf16 bf16x8 __attribute__((ext_vector_type(8)));
typedef __bf16 bf16x4 __attribute__((ext_vector_type(4)));
typedef float  f32x4  __attribute__((ext_vector_type(4)));

// ---------------- aux kernels ----------------

__global__ void cvt_f32_bf16(const float* __restrict__ in, bf16_t* __restrict__ out, int n4) {
  int i = blockIdx.x * blockDim.x + threadIdx.x;
  if (i < n4) {
    const f32x4 v = ((const f32x4*)in)[i];
    bf16x4 o;
    o[0] = (bf16_t)v[0]; o[1] = (bf16_t)v[1]; o[2] = (bf16_t)v[2]; o[3] = (bf16_t)v[3];
    ((bf16x4*)out)[i] = o;
  }
}

// in: [rows][cols] f32  ->  out: [cols][rows] bf16   (B^T layout for GEMM)
__global__ void transpose_cvt(const float* __restrict__ in, bf16_t* __restrict__ out,
                              int rows, int cols) {
  __shared__ float tile[32][33];
  const int tx = threadIdx.x, ty = threadIdx.y;
  const int x = blockIdx.x * 32 + tx;
#pragma unroll
  for (int i = 0; i < 32; i += 8) {
    int y = blockIdx.y * 32 + ty + i;
    tile[ty + i][tx] = in[(size_t)y * cols + x];
  }
  __syncthreads();
  const int xo = blockIdx.y * 32 + tx;
#pragma unroll
  for (int i = 0; i < 32; i += 8) {
    int yo = blockIdx.x * 32 + ty + i;
    out[(size_t)yo * rows + xo] = (bf16_t)tile[tx][ty + i];
  }
}

// multiplicity counts, packed 8 x 4-bit nibbles per u32. Per-row histogram in
// LDS (global-atomic version was 90us: 4.2M random global atomics, 92MB
// partial-line writes; LDS version = 32MB clean traffic).
#define ROWS_PER_BLK 4
__global__ __launch_bounds__(256) void count_scatter_lds(
    const int* __restrict__ idx, unsigned int* __restrict__ M) {
  __shared__ unsigned int loc[ROWS_PER_BLK * (D_FFN / 8)];   // 4 rows x 512 u32 = 8 KB
  const int t = threadIdx.x;
  const int r0 = blockIdx.x * ROWS_PER_BLK;

#pragma unroll
  for (int i = 0; i < ROWS_PER_BLK * (D_FFN / 8) / 256; ++i)
    loc[t + i * 256] = 0;
  __syncthreads();

  const int* ip = idx + (size_t)r0 * K_TOP;
#pragma unroll
  for (int i = 0; i < ROWS_PER_BLK * K_TOP / 256; ++i) {
    const int e = t + i * 256;            // 0..2047, coalesced
    const int lr = e >> 9;                // local row (K_TOP=512)
    const int j = ip[e];
    atomicAdd(&loc[lr * (D_FFN / 8) + (j >> 3)], 1u << ((j & 7) * 4));
  }
  __syncthreads();

  unsigned int* op = M + (size_t)r0 * (D_FFN / 8);
#pragma unroll
  for (int i = 0; i < ROWS_PER_BLK * (D_FFN / 8) / 256; ++i)
    op[t + i * 256] = loc[t + i * 256];
}

// ---------------- GEMM common ----------------

#define BK 32

__device__ __forceinline__ void gload_lds16(const void* g, void* l) {
#if __has_builtin(__builtin_amdgcn_global_load_lds)
  __builtin_amdgcn_global_load_lds((__attribute__((address_space(1))) void*)(g),
                                   (__attribute__((address_space(3))) void*)(l), 16, 0, 0);
#else
  *(bf16x8*)l = *(const bf16x8*)g;  // fallback: reg staging
#endif
}

// ---------------- GEMM1: gate+up fused, 128x128 tile, 512 thr / 8 waves ----
// Wave-tile 64x32 (wr=w>>2, wc=w&3): per-thread acc = 2*(4x2) f32x4 = 64 VGPR
// (dual-acc floor is 128 VGPR at 4x4 — that config can't reach 3 waves/SIMD;
//  DO NOT cap launch bounds below acc floor: R3 spilled at cap=170, 84 VGPR,
//  520 MB scratch writes, MfmaUtil 1%.)
#define BM1 128
#define BN1 128

__global__ __launch_bounds__(512, 4) void gemm_gateup(
    const bf16_t* __restrict__ A,    // [N_TOK][D_MODEL]
    const bf16_t* __restrict__ Bg,   // [D_FFN][D_MODEL]  (w_gate^T)
    const bf16_t* __restrict__ Bu,   // [D_FFN][D_MODEL]  (w_up^T)
    const unsigned int* __restrict__ cnt,  // [N_TOK][D_FFN/8] nibble counts
    bf16_t* __restrict__ Z,          // [N_TOK][NHALF]
    int n_base)                      // 0 or NHALF
{
  __shared__ alignas(16) bf16_t As[BM1 * BK];
  __shared__ alignas(16) bf16_t Bgs[BN1 * BK];
  __shared__ alignas(16) bf16_t Bus[BN1 * BK];

  const int m0 = blockIdx.x * BM1;
  const int n0 = blockIdx.y * BN1;        // local within half
  const int t = threadIdx.x;
  const int lane = t & 63;
  const int w = t >> 6;                   // 0..7
  const int wr = w >> 2, wc = w & 3;      // 2 x 4 wave grid; wave-tile 64x32
  const int l15 = lane & 15;
  const int kk = (lane >> 4) * 8;

  // staging: 512 threads, 1 x 16B slot per matrix per thread per K-step
  const int rowi = t >> 2;          // 0..127
  const int coli = (t & 3) * 8;
  const bf16_t* pA  = A  + (size_t)(m0 + rowi) * D_MODEL + coli;
  const bf16_t* pBg = Bg + (size_t)(n_base + n0 + rowi) * D_MODEL + coli;
  const bf16_t* pBu = Bu + (size_t)(n_base + n0 + rowi) * D_MODEL + coli;

  f32x4 accg[4][2] = {};
  f32x4 accu[4][2] = {};

  for (int k0 = 0; k0 < D_MODEL; k0 += BK) {
    gload_lds16(pA,  As  + t * 8);
    gload_lds16(pBg, Bgs + t * 8);
    gload_lds16(pBu, Bus + t * 8);
    pA += BK; pBg += BK; pBu += BK;
    __syncthreads();   // drains vmcnt (global_load_lds) + orders LDS

    bf16x8 af[4], bgf[2], buf[2];
#pragma unroll
    for (int m = 0; m < 4; ++m)
      af[m] = *(const bf16x8*)(As + (wr * 64 + m * 16 + l15) * BK + kk);
#pragma unroll
    for (int n = 0; n < 2; ++n) {
      bgf[n] = *(const bf16x8*)(Bgs + (wc * 32 + n * 16 + l15) * BK + kk);
      buf[n] = *(const bf16x8*)(Bus + (wc * 32 + n * 16 + l15) * BK + kk);
    }
#pragma unroll
    for (int m = 0; m < 4; ++m)
#pragma unroll
      for (int n = 0; n < 2; ++n) {
        accg[m][n] = __builtin_amdgcn_mfma_f32_16x16x32_bf16(af[m], bgf[n], accg[m][n], 0, 0, 0);
        accu[m][n] = __builtin_amdgcn_mfma_f32_16x16x32_bf16(af[m], buf[n], accu[m][n], 0, 0, 0);
      }
    __syncthreads();
  }

  // epilogue: Z = cnt * u * silu(g)   (C/D map: col=lane&15, row=(lane>>4)*4+j)
#pragma unroll
  for (int m = 0; m < 4; ++m) {
#pragma unroll
    for (int n = 0; n < 2; ++n) {
      const int colL = n0 + wc * 32 + n * 16 + l15;   // local col within half
      const int jg = n_base + colL;                   // global FFN index
#pragma unroll
      for (int j = 0; j < 4; ++j) {
        const int row = m0 + wr * 64 + m * 16 + (lane >> 4) * 4 + j;
        float g = accg[m][n][j];
        float u = accu[m][n][j];
        unsigned int cw = cnt[(size_t)row * (D_FFN / 8) + (jg >> 3)];
        float c = (float)((cw >> ((jg & 7) * 4)) & 15u);
        float z = c * u * (g / (1.0f + __expf(-g)));
        Z[(size_t)row * NHALF + colL] = (bf16_t)z;
      }
    }
  }
}

// ---------------- GEMM2: down, 64x128 tile (grid 1024 blocks) ----------------
// out (+)= Z(8192xNHALF) * w_down[k_base:k_base+NHALF, :]
#define BM2 64
#define BN2 128

__global__ __launch_bounds__(256, 4) void gemm_down(
    const bf16_t* __restrict__ A,    // Z [N_TOK][NHALF]
    const bf16_t* __restrict__ B,    // [D_MODEL][D_FFN]  (w_down^T)
    float* __restrict__ C,           // [N_TOK][D_MODEL]
    int k_base, int accum)
{
  __shared__ alignas(16) bf16_t As[BM2 * BK];
  __shared__ alignas(16) bf16_t Bs[BN2 * BK];

  const int m0 = blockIdx.x * BM2;
  const int n0 = blockIdx.y * BN2;
  const int t = threadIdx.x;
  const int lane = t & 63;
  const int w = t >> 6;
  const int wr = w >> 1, wc = w & 1;   // wave tile: 32 rows x 64 cols
  const int l15 = lane & 15;
  const int kk = (lane >> 4) * 8;

  const int rowi = t >> 2;          // 0..63
  const int coli = (t & 3) * 8;
  const bf16_t* pA = A + (size_t)(m0 + rowi) * NHALF + coli;             // 64 rows: 1 slot/thread
  const bf16_t* pB = B + (size_t)(n0 + rowi) * D_FFN + k_base + coli;    // 128 rows: 2 slots/thread
  const size_t rstepB = (size_t)64 * D_FFN;

  f32x4 acc[2][4] = {};

  for (int k0 = 0; k0 < NHALF; k0 += BK) {
    gload_lds16(pA,          As + t * 8);
    gload_lds16(pB,          Bs + t * 8);
    gload_lds16(pB + rstepB, Bs + (256 + t) * 8);
    pA += BK; pB += BK;
    __syncthreads();

    bf16x8 af[2], bf[4];
#pragma unroll
    for (int m = 0; m < 2; ++m)
      af[m] = *(const bf16x8*)(As + (wr * 32 + m * 16 + l15) * BK + kk);
#pragma unroll
    for (int n = 0; n < 4; ++n)
      bf[n] = *(const bf16x8*)(Bs + (wc * 64 + n * 16 + l15) * BK + kk);
#pragma unroll
    for (int m = 0; m < 2; ++m)
#pragma unroll
      for (int n = 0; n < 4; ++n)
        acc[m][n] = __builtin_amdgcn_mfma_f32_16x16x32_bf16(af[m], bf[n], acc[m][n], 0, 0, 0);
    __syncthreads();
  }

#pragma unroll
  for (int m = 0; m < 2; ++m) {
#pragma unroll
    for (int n = 0; n < 4; ++n) {
      const int col = n0 + wc * 64 + n * 16 + l15;
#pragma unroll
      for (int j = 0; j < 4; ++j) {
        const int row = m0 + wr * 32 + m * 16 + (lane >> 4) * 4 + j;
        const size_t off = (size_t)row * D_MODEL + col;
        float prev = accum ? C[off] : 0.0f;
        C[off] = prev + acc[m][n][j];
      }
    }
  }
}

// ---------------- launch ----------------

extern "C" void kernel_launch(void* const* d_in, const int* in_sizes, int n_in,
                              void* d_out, int out_size, void* d_ws, size_t ws_size,
                              hipStream_t stream) {
  const float* x  = (const float*)d_in[0];
  const int*   idx = (const int*)d_in[1];
  const float* wg = (const float*)d_in[2];
  const float* wu = (const float*)d_in[3];
  const float* wd = (const float*)d_in[4];
  float* out = (float*)d_out;

  char* ws = (char*)d_ws;
  const size_t SZ_XB  = (size_t)N_TOK * D_MODEL * 2;   // 16 MB
  const size_t SZ_W   = (size_t)D_MODEL * D_FFN * 2;   //  8 MB each
  const size_t SZ_CNT = (size_t)N_TOK * D_FFN / 2;     // 16 MB (4-bit counts)
  bf16_t* xb  = (bf16_t*)(ws);
  bf16_t* wgT = (bf16_t*)(ws + SZ_XB);
  bf16_t* wuT = (bf16_t*)(ws + SZ_XB + SZ_W);
  bf16_t* wdT = (bf16_t*)(ws + SZ_XB + 2 * SZ_W);
  unsigned int* cnt = (unsigned int*)(ws + SZ_XB + 3 * SZ_W);
  bf16_t* Z   = (bf16_t*)(ws + SZ_XB + 3 * SZ_W + SZ_CNT);  // [N_TOK][NHALF]
  // total ws use: 16 + 24 + 16 + 32 = 88 MB

  // cnt map fully overwritten by count_scatter_lds (no memset needed)
  count_scatter_lds<<<N_TOK / ROWS_PER_BLK, 256, 0, stream>>>(idx, cnt);
  cvt_f32_bf16<<<(N_TOK * D_MODEL / 4 + 255) / 256, 256, 0, stream>>>(x, xb, N_TOK * D_MODEL / 4);
  transpose_cvt<<<dim3(D_FFN / 32, D_MODEL / 32), dim3(32, 8), 0, stream>>>(wg, wgT, D_MODEL, D_FFN);
  transpose_cvt<<<dim3(D_FFN / 32, D_MODEL / 32), dim3(32, 8), 0, stream>>>(wu, wuT, D_MODEL, D_FFN);
  transpose_cvt<<<dim3(D_MODEL / 32, D_FFN / 32), dim3(32, 8), 0, stream>>>(wd, wdT, D_FFN, D_MODEL);

  // two FFN halves, Z buffer reused (stream-ordered)
  gemm_gateup<<<dim3(N_TOK / BM1, NHALF / BN1), 512, 0, stream>>>(xb, wgT, wuT, cnt, Z, 0);
  gemm_down<<<dim3(N_TOK / BM2, D_MODEL / BN2), 256, 0, stream>>>(Z, wdT, out, 0, 0);
  gemm_gateup<<<dim3(N_TOK / BM1, NHALF / BN1), 512, 0, stream>>>(xb, wgT, wuT, cnt, Z, NHALF);
  gemm_down<<<dim3(N_TOK / BM2, D_MODEL / BN2), 256, 0, stream>>>(Z, wdT, out, NHALF, 1);
}

// Round 6
// 298.010 us; speedup vs baseline: 2.1567x; 1.0436x over previous
//
#include <hip/hip_runtime.h>
#include <hip/hip_bf16.h>
#include <cstdint>
#include <cstddef>

#define N_TOK   8192
#define D_MODEL 1024
#define D_FFN   4096
#define K_TOP   512
#define NHALF   2048   // FFN half-width processed per round

typedef __bf16 bf16_t;
typedef __bf16 bf16x8 __attribute__((ext_vector_type(8)));
typedef __bf16 bf16x4 __attribute__((ext_vector_type(4)));
typedef float  f32x4  __attribute__((ext_vector_type(4)));

// ---------------- aux kernels ----------------

__global__ void cvt_f32_bf16(const float* __restrict__ in, bf16_t* __restrict__ out, int n4) {
  int i = blockIdx.x * blockDim.x + threadIdx.x;
  if (i < n4) {
    const f32x4 v = ((const f32x4*)in)[i];
    bf16x4 o;
    o[0] = (bf16_t)v[0]; o[1] = (bf16_t)v[1]; o[2] = (bf16_t)v[2]; o[3] = (bf16_t)v[3];
    ((bf16x4*)out)[i] = o;
  }
}

// in: [rows][cols] f32  ->  out: [cols][rows] bf16   (B^T layout for GEMM)
__global__ void transpose_cvt(const float* __restrict__ in, bf16_t* __restrict__ out,
                              int rows, int cols) {
  __shared__ float tile[32][33];
  const int tx = threadIdx.x, ty = threadIdx.y;
  const int x = blockIdx.x * 32 + tx;
#pragma unroll
  for (int i = 0; i < 32; i += 8) {
    int y = blockIdx.y * 32 + ty + i;
    tile[ty + i][tx] = in[(size_t)y * cols + x];
  }
  __syncthreads();
  const int xo = blockIdx.y * 32 + tx;
#pragma unroll
  for (int i = 0; i < 32; i += 8) {
    int yo = blockIdx.x * 32 + ty + i;
    out[(size_t)yo * rows + xo] = (bf16_t)tile[tx][ty + i];
  }
}

// multiplicity counts, packed 8 x 4-bit nibbles per u32, per-row LDS histogram
#define ROWS_PER_BLK 4
__global__ __launch_bounds__(256) void count_scatter_lds(
    const int* __restrict__ idx, unsigned int* __restrict__ M) {
  __shared__ unsigned int loc[ROWS_PER_BLK * (D_FFN / 8)];   // 8 KB
  const int t = threadIdx.x;
  const int r0 = blockIdx.x * ROWS_PER_BLK;

#pragma unroll
  for (int i = 0; i < ROWS_PER_BLK * (D_FFN / 8) / 256; ++i)
    loc[t + i * 256] = 0;
  __syncthreads();

  const int* ip = idx + (size_t)r0 * K_TOP;
#pragma unroll
  for (int i = 0; i < ROWS_PER_BLK * K_TOP / 256; ++i) {
    const int e = t + i * 256;
    const int lr = e >> 9;
    const int j = ip[e];
    atomicAdd(&loc[lr * (D_FFN / 8) + (j >> 3)], 1u << ((j & 7) * 4));
  }
  __syncthreads();

  unsigned int* op = M + (size_t)r0 * (D_FFN / 8);
#pragma unroll
  for (int i = 0; i < ROWS_PER_BLK * (D_FFN / 8) / 256; ++i)
    op[t + i * 256] = loc[t + i * 256];
}

// ---------------- GEMM common ----------------

__device__ __forceinline__ void gload_lds16(const void* g, void* l) {
#if __has_builtin(__builtin_amdgcn_global_load_lds)
  __builtin_amdgcn_global_load_lds((__attribute__((address_space(1))) void*)(g),
                                   (__attribute__((address_space(3))) void*)(l), 16, 0, 0);
#else
  *(bf16x8*)l = *(const bf16x8*)g;
#endif
}

// ---------------- GEMM1: gate+up fused, 8-phase 256x128 template ----------
// 8 waves (4M x 2N), per-wave 64x64 per matrix; acc = 2*64 = 128 VGPR.
// LDS 128 KiB: 2 dbuf x { A 32K | Bg 16K | Bu 16K }, dynamic shared.
// T2 swizzle: logical (row r, col16 cb) lives at byte r*128 + (cb^(r&7))*16;
// stage keeps LDS dest LINEAR and inverse-swizzles the per-lane GLOBAL src
// (rule #21: same involution both sides).
// Phase: {ds_read frags || 2 gload_lds -> s_barrier -> lgkmcnt(0)+sched_barrier
//         -> setprio(1) 16 MFMA setprio(0) -> s_barrier}; vmcnt(0) once/K-tile.
#define BM1 256
#define BN1 128
#define BK1 64
#define NT1 (D_MODEL / BK1)   // 16 K-tiles
#define LDSBUF 65536          // bytes per double-buffer half

__global__ __launch_bounds__(512, 2) void gemm_gateup_8p(
    const bf16_t* __restrict__ A,    // [N_TOK][D_MODEL]
    const bf16_t* __restrict__ Bg,   // [D_FFN][D_MODEL]
    const bf16_t* __restrict__ Bu,   // [D_FFN][D_MODEL]
    const unsigned int* __restrict__ cnt,
    bf16_t* __restrict__ Z,          // [N_TOK][NHALF]
    int n_base)
{
  extern __shared__ char smem[];
  const int t = threadIdx.x;
  const int lane = t & 63;
  const int w = t >> 6;            // 0..7
  const int wr = w >> 1;           // 0..3 (M)
  const int wc = w & 1;            // 0..1 (N)
  const int l15 = lane & 15;
  const int grp = lane >> 4;       // 0..3
  const int m0 = blockIdx.x * BM1;
  const int n0 = blockIdx.y * BN1;

  // ---- stage: per-lane global element-offsets (inverse-swizzled) ----
  int offA[4], offB[2];
#pragma unroll
  for (int c = 0; c < 4; ++c) {
    const int s = c * 512 + w * 64 + lane;          // A slot 0..2047
    const int r = s >> 3, cb = (s & 7) ^ (r & 7);
    offA[c] = (m0 + r) * D_MODEL + cb * 8;
  }
#pragma unroll
  for (int c = 0; c < 2; ++c) {
    const int s = c * 512 + w * 64 + lane;          // B slot 0..1023
    const int r = s >> 3, cb = (s & 7) ^ (r & 7);
    offB[c] = (n_base + n0 + r) * D_MODEL + cb * 8;
  }
  const int dst0 = (w * 64 + lane) * 16;            // linear LDS dest (bytes)

  // ---- ds_read byte offsets (swizzled) ----
  const int swz = l15 & 7;
  const int a_k0 = wr * 8192 + l15 * 128 + ((0 + grp) ^ swz) * 16;
  const int a_k1 = wr * 8192 + l15 * 128 + ((4 + grp) ^ swz) * 16;
  const int bg_k0 = 32768 + wc * 8192 + l15 * 128 + ((0 + grp) ^ swz) * 16;
  const int bg_k1 = 32768 + wc * 8192 + l15 * 128 + ((4 + grp) ^ swz) * 16;
  const int bu_k0 = bg_k0 + 16384;
  const int bu_k1 = bg_k1 + 16384;

  // ---- prologue: stage K-tile 0 into buffer 0 ----
#pragma unroll
  for (int c = 0; c < 4; ++c) gload_lds16(A + offA[c], smem + dst0 + c * 8192);
#pragma unroll
  for (int c = 0; c < 2; ++c) gload_lds16(Bg + offB[c], smem + 32768 + dst0 + c * 8192);
#pragma unroll
  for (int c = 0; c < 2; ++c) gload_lds16(Bu + offB[c], smem + 49152 + dst0 + c * 8192);
  asm volatile("s_waitcnt vmcnt(0)" ::: "memory");
  __builtin_amdgcn_s_barrier();

  f32x4 accg[4][4] = {};
  f32x4 accu[4][4] = {};

#define MFMA16(ACC, AF, BF)                                                      \
  _Pragma("unroll")                                                              \
  for (int m = 0; m < 4; ++m)                                                    \
    _Pragma("unroll")                                                            \
    for (int n = 0; n < 4; ++n)                                                  \
      ACC[m][n] = __builtin_amdgcn_mfma_f32_16x16x32_bf16(AF[m], BF[n], ACC[m][n], 0, 0, 0);

#define PHASE_SYNC_PRE()                                                         \
  __builtin_amdgcn_s_barrier();                                                  \
  asm volatile("s_waitcnt lgkmcnt(0)" ::: "memory");                             \
  __builtin_amdgcn_sched_barrier(0);                                             \
  __builtin_amdgcn_s_setprio(1);

#define PHASE_SYNC_POST()                                                        \
  __builtin_amdgcn_s_setprio(0);                                                 \
  __builtin_amdgcn_s_barrier();

  for (int tt = 0; tt < NT1; ++tt) {
    char* rb = smem + (tt & 1) * LDSBUF;
    char* wb = smem + ((tt & 1) ^ 1) * LDSBUF;
    const int kg = (tt + 1) * BK1;              // next tile's k offset (elements)
    const bool st = (tt + 1 < NT1);
    bf16x8 af[4], bgf[4], buf_[4];

    // ---- P1: G x k0 ----
#pragma unroll
    for (int m = 0; m < 4; ++m) af[m] = *(const bf16x8*)(rb + a_k0 + m * 2048);
#pragma unroll
    for (int n = 0; n < 4; ++n) bgf[n] = *(const bf16x8*)(rb + bg_k0 + n * 2048);
    if (st) {
      gload_lds16(A + offA[0] + kg, wb + dst0);
      gload_lds16(A + offA[1] + kg, wb + dst0 + 8192);
    }
    PHASE_SYNC_PRE();
    MFMA16(accg, af, bgf);
    PHASE_SYNC_POST();

    // ---- P2: U x k0 ----
#pragma unroll
    for (int n = 0; n < 4; ++n) buf_[n] = *(const bf16x8*)(rb + bu_k0 + n * 2048);
    if (st) {
      gload_lds16(A + offA[2] + kg, wb + dst0 + 16384);
      gload_lds16(A + offA[3] + kg, wb + dst0 + 24576);
    }
    PHASE_SYNC_PRE();
    MFMA16(accu, af, buf_);
    PHASE_SYNC_POST();

    // ---- P3: G x k1 ----
#pragma unroll
    for (int m = 0; m < 4; ++m) af[m] = *(const bf16x8*)(rb + a_k1 + m * 2048);
#pragma unroll
    for (int n = 0; n < 4; ++n) bgf[n] = *(const bf16x8*)(rb + bg_k1 + n * 2048);
    if (st) {
      gload_lds16(Bg + offB[0] + kg, wb + 32768 + dst0);
      gload_lds16(Bg + offB[1] + kg, wb + 32768 + dst0 + 8192);
    }
    PHASE_SYNC_PRE();
    MFMA16(accg, af, bgf);
    PHASE_SYNC_POST();

    // ---- P4: U x k1 ----
#pragma unroll
    for (int n = 0; n < 4; ++n) buf_[n] = *(const bf16x8*)(rb + bu_k1 + n * 2048);
    if (st) {
      gload_lds16(Bu + offB[0] + kg, wb + 49152 + dst0);
      gload_lds16(Bu + offB[1] + kg, wb + 49152 + dst0 + 8192);
    }
    __builtin_amdgcn_s_barrier();
    asm volatile("s_waitcnt lgkmcnt(0)" ::: "memory");
    __builtin_amdgcn_sched_barrier(0);
    __builtin_amdgcn_s_setprio(1);
    MFMA16(accu, af, buf_);
    __builtin_amdgcn_s_setprio(0);
    // end-of-iter: next tile's 8 loads must be resident before it is read
    if (st) asm volatile("s_waitcnt vmcnt(0)" ::: "memory");
    __builtin_amdgcn_s_barrier();
  }

  // ---- epilogue: Z = cnt * u * silu(g) ----
#pragma unroll
  for (int m = 0; m < 4; ++m) {
#pragma unroll
    for (int n = 0; n < 4; ++n) {
      const int colL = n0 + wc * 64 + n * 16 + l15;
      const int jg = n_base + colL;
#pragma unroll
      for (int j = 0; j < 4; ++j) {
        const int row = m0 + wr * 64 + m * 16 + grp * 4 + j;
        float g = accg[m][n][j];
        float u = accu[m][n][j];
        unsigned int cw = cnt[(size_t)row * (D_FFN / 8) + (jg >> 3)];
        float c = (float)((cw >> ((jg & 7) * 4)) & 15u);
        float z = c * u * (g / (1.0f + __expf(-g)));
        Z[(size_t)row * NHALF + colL] = (bf16_t)z;
      }
    }
  }
#undef MFMA16
#undef PHASE_SYNC_PRE
#undef PHASE_SYNC_POST
}

// ---------------- GEMM2: down, 64x128 tile (unchanged, passing) ------------
#define BK 32
#define BM2 64
#define BN2 128

__global__ __launch_bounds__(256, 4) void gemm_down(
    const bf16_t* __restrict__ A,    // Z [N_TOK][NHALF]
    const bf16_t* __restrict__ B,    // [D_MODEL][D_FFN]  (w_down^T)
    float* __restrict__ C,           // [N_TOK][D_MODEL]
    int k_base, int accum)
{
  __shared__ alignas(16) bf16_t As[BM2 * BK];
  __shared__ alignas(16) bf16_t Bs[BN2 * BK];

  const int m0 = blockIdx.x * BM2;
  const int n0 = blockIdx.y * BN2;
  const int t = threadIdx.x;
  const int lane = t & 63;
  const int w = t >> 6;
  const int wr = w >> 1, wc = w & 1;
  const int l15 = lane & 15;
  const int kk = (lane >> 4) * 8;

  const int rowi = t >> 2;
  const int coli = (t & 3) * 8;
  const bf16_t* pA = A + (size_t)(m0 + rowi) * NHALF + coli;
  const bf16_t* pB = B + (size_t)(n0 + rowi) * D_FFN + k_base + coli;
  const size_t rstepB = (size_t)64 * D_FFN;

  f32x4 acc[2][4] = {};

  for (int k0 = 0; k0 < NHALF; k0 += BK) {
    gload_lds16(pA,          As + t * 8);
    gload_lds16(pB,          Bs + t * 8);
    gload_lds16(pB + rstepB, Bs + (256 + t) * 8);
    pA += BK; pB += BK;
    __syncthreads();

    bf16x8 af[2], bf[4];
#pragma unroll
    for (int m = 0; m < 2; ++m)
      af[m] = *(const bf16x8*)(As + (wr * 32 + m * 16 + l15) * BK + kk);
#pragma unroll
    for (int n = 0; n < 4; ++n)
      bf[n] = *(const bf16x8*)(Bs + (wc * 64 + n * 16 + l15) * BK + kk);
#pragma unroll
    for (int m = 0; m < 2; ++m)
#pragma unroll
      for (int n = 0; n < 4; ++n)
        acc[m][n] = __builtin_amdgcn_mfma_f32_16x16x32_bf16(af[m], bf[n], acc[m][n], 0, 0, 0);
    __syncthreads();
  }

#pragma unroll
  for (int m = 0; m < 2; ++m) {
#pragma unroll
    for (int n = 0; n < 4; ++n) {
      const int col = n0 + wc * 64 + n * 16 + l15;
#pragma unroll
      for (int j = 0; j < 4; ++j) {
        const int row = m0 + wr * 32 + m * 16 + (lane >> 4) * 4 + j;
        const size_t off = (size_t)row * D_MODEL + col;
        float prev = accum ? C[off] : 0.0f;
        C[off] = prev + acc[m][n][j];
      }
    }
  }
}

// ---------------- launch ----------------

extern "C" void kernel_launch(void* const* d_in, const int* in_sizes, int n_in,
                              void* d_out, int out_size, void* d_ws, size_t ws_size,
                              hipStream_t stream) {
  const float* x  = (const float*)d_in[0];
  const int*   idx = (const int*)d_in[1];
  const float* wg = (const float*)d_in[2];
  const float* wu = (const float*)d_in[3];
  const float* wd = (const float*)d_in[4];
  float* out = (float*)d_out;

  char* ws = (char*)d_ws;
  const size_t SZ_XB  = (size_t)N_TOK * D_MODEL * 2;   // 16 MB
  const size_t SZ_W   = (size_t)D_MODEL * D_FFN * 2;   //  8 MB each
  const size_t SZ_CNT = (size_t)N_TOK * D_FFN / 2;     // 16 MB
  bf16_t* xb  = (bf16_t*)(ws);
  bf16_t* wgT = (bf16_t*)(ws + SZ_XB);
  bf16_t* wuT = (bf16_t*)(ws + SZ_XB + SZ_W);
  bf16_t* wdT = (bf16_t*)(ws + SZ_XB + 2 * SZ_W);
  unsigned int* cnt = (unsigned int*)(ws + SZ_XB + 3 * SZ_W);
  bf16_t* Z   = (bf16_t*)(ws + SZ_XB + 3 * SZ_W + SZ_CNT);  // [N_TOK][NHALF]
  // total ws use: 16 + 24 + 16 + 32 = 88 MB

  // allow 128 KiB dynamic LDS for the 8-phase kernel (idempotent)
  (void)hipFuncSetAttribute((const void*)gemm_gateup_8p,
                            hipFuncAttributeMaxDynamicSharedMemorySize, 131072);

  count_scatter_lds<<<N_TOK / ROWS_PER_BLK, 256, 0, stream>>>(idx, cnt);
  cvt_f32_bf16<<<(N_TOK * D_MODEL / 4 + 255) / 256, 256, 0, stream>>>(x, xb, N_TOK * D_MODEL / 4);
  transpose_cvt<<<dim3(D_FFN / 32, D_MODEL / 32), dim3(32, 8), 0, stream>>>(wg, wgT, D_MODEL, D_FFN);
  transpose_cvt<<<dim3(D_FFN / 32, D_MODEL / 32), dim3(32, 8), 0, stream>>>(wu, wuT, D_MODEL, D_FFN);
  transpose_cvt<<<dim3(D_MODEL / 32, D_FFN / 32), dim3(32, 8), 0, stream>>>(wd, wdT, D_FFN, D_MODEL);

  // two FFN halves, Z buffer reused (stream-ordered)
  gemm_gateup_8p<<<dim3(N_TOK / BM1, NHALF / BN1), 512, 131072, stream>>>(xb, wgT, wuT, cnt, Z, 0);
  gemm_down<<<dim3(N_TOK / BM2, D_MODEL / BN2), 256, 0, stream>>>(Z, wdT, out, 0, 0);
  gemm_gateup_8p<<<dim3(N_TOK / BM1, NHALF / BN1), 512, 131072, stream>>>(xb, wgT, wuT, cnt, Z, NHALF);
  gemm_down<<<dim3(N_TOK / BM2, D_MODEL / BN2), 256, 0, stream>>>(Z, wdT, out, NHALF, 1);
}

// Round 7
// 270.216 us; speedup vs baseline: 2.3786x; 1.1029x over previous
//
#include <hip/hip_runtime.h>
#include <hip/hip_bf16.h>
#include <cstdint>
#include <cstddef>

#define N_TOK   8192
#define D_MODEL 1024
#define D_FFN   4096
#define K_TOP   512
#define NHALF   2048   // FFN half-width processed per round

typedef __bf16 bf16_t;
typedef __bf16 bf16x8 __attribute__((ext_vector_type(8)));
typedef __bf16 bf16x4 __attribute__((ext_vector_type(4)));
typedef float  f32x4  __attribute__((ext_vector_type(4)));

// ---------------- aux kernels ----------------

__global__ void cvt_f32_bf16(const float* __restrict__ in, bf16_t* __restrict__ out, int n4) {
  int i = blockIdx.x * blockDim.x + threadIdx.x;
  if (i < n4) {
    const f32x4 v = ((const f32x4*)in)[i];
    bf16x4 o;
    o[0] = (bf16_t)v[0]; o[1] = (bf16_t)v[1]; o[2] = (bf16_t)v[2]; o[3] = (bf16_t)v[3];
    ((bf16x4*)out)[i] = o;
  }
}

// in: [rows][cols] f32  ->  out: [cols][rows] bf16   (B^T layout for GEMM)
__global__ void transpose_cvt(const float* __restrict__ in, bf16_t* __restrict__ out,
                              int rows, int cols) {
  __shared__ float tile[32][33];
  const int tx = threadIdx.x, ty = threadIdx.y;
  const int x = blockIdx.x * 32 + tx;
#pragma unroll
  for (int i = 0; i < 32; i += 8) {
    int y = blockIdx.y * 32 + ty + i;
    tile[ty + i][tx] = in[(size_t)y * cols + x];
  }
  __syncthreads();
  const int xo = blockIdx.y * 32 + tx;
#pragma unroll
  for (int i = 0; i < 32; i += 8) {
    int yo = blockIdx.x * 32 + ty + i;
    out[(size_t)yo * rows + xo] = (bf16_t)tile[tx][ty + i];
  }
}

// multiplicity counts, packed 8 x 4-bit nibbles per u32, per-row LDS histogram
#define ROWS_PER_BLK 4
__global__ __launch_bounds__(256) void count_scatter_lds(
    const int* __restrict__ idx, unsigned int* __restrict__ M) {
  __shared__ unsigned int loc[ROWS_PER_BLK * (D_FFN / 8)];   // 8 KB
  const int t = threadIdx.x;
  const int r0 = blockIdx.x * ROWS_PER_BLK;

#pragma unroll
  for (int i = 0; i < ROWS_PER_BLK * (D_FFN / 8) / 256; ++i)
    loc[t + i * 256] = 0;
  __syncthreads();

  const int* ip = idx + (size_t)r0 * K_TOP;
#pragma unroll
  for (int i = 0; i < ROWS_PER_BLK * K_TOP / 256; ++i) {
    const int e = t + i * 256;
    const int lr = e >> 9;
    const int j = ip[e];
    atomicAdd(&loc[lr * (D_FFN / 8) + (j >> 3)], 1u << ((j & 7) * 4));
  }
  __syncthreads();

  unsigned int* op = M + (size_t)r0 * (D_FFN / 8);
#pragma unroll
  for (int i = 0; i < ROWS_PER_BLK * (D_FFN / 8) / 256; ++i)
    op[t + i * 256] = loc[t + i * 256];
}

// ---------------- GEMM common ----------------

__device__ __forceinline__ void gload_lds16(const void* g, void* l) {
#if __has_builtin(__builtin_amdgcn_global_load_lds)
  __builtin_amdgcn_global_load_lds((__attribute__((address_space(1))) void*)(g),
                                   (__attribute__((address_space(3))) void*)(l), 16, 0, 0);
#else
  *(bf16x8*)l = *(const bf16x8*)g;
#endif
}

#define MFMA16(ACC, AF, BF)                                                      \
  _Pragma("unroll")                                                              \
  for (int m = 0; m < 4; ++m)                                                    \
    _Pragma("unroll")                                                            \
    for (int n = 0; n < 4; ++n)                                                  \
      ACC[m][n] = __builtin_amdgcn_mfma_f32_16x16x32_bf16(AF[m], BF[n], ACC[m][n], 0, 0, 0);

#define PHASE_SYNC_PRE()                                                         \
  __builtin_amdgcn_s_barrier();                                                  \
  asm volatile("s_waitcnt lgkmcnt(0)" ::: "memory");                             \
  __builtin_amdgcn_sched_barrier(0);                                             \
  __builtin_amdgcn_s_setprio(1);

#define PHASE_SYNC_POST()                                                        \
  __builtin_amdgcn_s_setprio(0);                                                 \
  __builtin_amdgcn_s_barrier();

// ---------------- GEMM1: gate+up fused, 8-phase 256x128 template ----------
// 8 waves (4M x 2N), per-wave 64x64 per matrix; acc = 2*64 = 128 VGPR.
// LDS 128 KiB: 2 dbuf x { A 32K | Bg 16K | Bu 16K }, dynamic shared.
// T2 swizzle (verified R6: conflicts 8.4M -> 0): logical (row r, col16 cb) at
// byte r*128 + (cb^(r&7))*16; LDS dest LINEAR, inverse-swizzle the global src.
// T4 (this round): ALL of tile t+1's loads issue in P1 -> end-of-iter vmcnt(0)
// has ~3.5 phases of cover (R6 spread them P1-P4; P4's loads stalled the drain).
#define BM1 256
#define BN1 128
#define BK1 64
#define NT1 (D_MODEL / BK1)   // 16 K-tiles
#define LDSBUF 65536          // bytes per double-buffer half

__global__ __launch_bounds__(512, 2) void gemm_gateup_8p(
    const bf16_t* __restrict__ A,    // [N_TOK][D_MODEL]
    const bf16_t* __restrict__ Bg,   // [D_FFN][D_MODEL]
    const bf16_t* __restrict__ Bu,   // [D_FFN][D_MODEL]
    const unsigned int* __restrict__ cnt,
    bf16_t* __restrict__ Z,          // [N_TOK][NHALF]
    int n_base)
{
  extern __shared__ char smem[];
  const int t = threadIdx.x;
  const int lane = t & 63;
  const int w = t >> 6;            // 0..7
  const int wr = w >> 1;           // 0..3 (M)
  const int wc = w & 1;            // 0..1 (N)
  const int l15 = lane & 15;
  const int grp = lane >> 4;       // 0..3
  const int m0 = blockIdx.x * BM1;
  const int n0 = blockIdx.y * BN1;

  // ---- stage: per-lane global element-offsets (inverse-swizzled) ----
  int offA[4], offB[2];
#pragma unroll
  for (int c = 0; c < 4; ++c) {
    const int s = c * 512 + w * 64 + lane;          // A slot 0..2047
    const int r = s >> 3, cb = (s & 7) ^ (r & 7);
    offA[c] = (m0 + r) * D_MODEL + cb * 8;
  }
#pragma unroll
  for (int c = 0; c < 2; ++c) {
    const int s = c * 512 + w * 64 + lane;          // B slot 0..1023
    const int r = s >> 3, cb = (s & 7) ^ (r & 7);
    offB[c] = (n_base + n0 + r) * D_MODEL + cb * 8;
  }
  const int dst0 = (w * 64 + lane) * 16;            // linear LDS dest (bytes)

  // ---- ds_read byte offsets (swizzled) ----
  const int swz = l15 & 7;
  const int a_k0 = wr * 8192 + l15 * 128 + ((0 + grp) ^ swz) * 16;
  const int a_k1 = wr * 8192 + l15 * 128 + ((4 + grp) ^ swz) * 16;
  const int bg_k0 = 32768 + wc * 8192 + l15 * 128 + ((0 + grp) ^ swz) * 16;
  const int bg_k1 = 32768 + wc * 8192 + l15 * 128 + ((4 + grp) ^ swz) * 16;
  const int bu_k0 = bg_k0 + 16384;
  const int bu_k1 = bg_k1 + 16384;

  // ---- prologue: stage K-tile 0 into buffer 0 ----
#pragma unroll
  for (int c = 0; c < 4; ++c) gload_lds16(A + offA[c], smem + dst0 + c * 8192);
#pragma unroll
  for (int c = 0; c < 2; ++c) gload_lds16(Bg + offB[c], smem + 32768 + dst0 + c * 8192);
#pragma unroll
  for (int c = 0; c < 2; ++c) gload_lds16(Bu + offB[c], smem + 49152 + dst0 + c * 8192);
  asm volatile("s_waitcnt vmcnt(0)" ::: "memory");
  __builtin_amdgcn_s_barrier();

  f32x4 accg[4][4] = {};
  f32x4 accu[4][4] = {};

  for (int tt = 0; tt < NT1; ++tt) {
    char* rb = smem + (tt & 1) * LDSBUF;
    char* wb = smem + ((tt & 1) ^ 1) * LDSBUF;
    const int kg = (tt + 1) * BK1;              // next tile's k offset (elements)
    const bool st = (tt + 1 < NT1);
    bf16x8 af[4], bgf[4], buf_[4];

    // ---- P1: G x k0  (+ ALL next-tile staging: T4 issue-early) ----
#pragma unroll
    for (int m = 0; m < 4; ++m) af[m] = *(const bf16x8*)(rb + a_k0 + m * 2048);
#pragma unroll
    for (int n = 0; n < 4; ++n) bgf[n] = *(const bf16x8*)(rb + bg_k0 + n * 2048);
    if (st) {
#pragma unroll
      for (int c = 0; c < 4; ++c) gload_lds16(A + offA[c] + kg, wb + dst0 + c * 8192);
#pragma unroll
      for (int c = 0; c < 2; ++c) gload_lds16(Bg + offB[c] + kg, wb + 32768 + dst0 + c * 8192);
#pragma unroll
      for (int c = 0; c < 2; ++c) gload_lds16(Bu + offB[c] + kg, wb + 49152 + dst0 + c * 8192);
    }
    PHASE_SYNC_PRE();
    MFMA16(accg, af, bgf);
    PHASE_SYNC_POST();

    // ---- P2: U x k0 ----
#pragma unroll
    for (int n = 0; n < 4; ++n) buf_[n] = *(const bf16x8*)(rb + bu_k0 + n * 2048);
    PHASE_SYNC_PRE();
    MFMA16(accu, af, buf_);
    PHASE_SYNC_POST();

    // ---- P3: G x k1 ----
#pragma unroll
    for (int m = 0; m < 4; ++m) af[m] = *(const bf16x8*)(rb + a_k1 + m * 2048);
#pragma unroll
    for (int n = 0; n < 4; ++n) bgf[n] = *(const bf16x8*)(rb + bg_k1 + n * 2048);
    PHASE_SYNC_PRE();
    MFMA16(accg, af, bgf);
    PHASE_SYNC_POST();

    // ---- P4: U x k1 ----
#pragma unroll
    for (int n = 0; n < 4; ++n) buf_[n] = *(const bf16x8*)(rb + bu_k1 + n * 2048);
    __builtin_amdgcn_s_barrier();
    asm volatile("s_waitcnt lgkmcnt(0)" ::: "memory");
    __builtin_amdgcn_sched_barrier(0);
    __builtin_amdgcn_s_setprio(1);
    MFMA16(accu, af, buf_);
    __builtin_amdgcn_s_setprio(0);
    // next tile's loads issued in P1 -> this drain is ~covered
    if (st) asm volatile("s_waitcnt vmcnt(0)" ::: "memory");
    __builtin_amdgcn_s_barrier();
  }

  // ---- epilogue: Z = cnt * u * silu(g) ----
#pragma unroll
  for (int m = 0; m < 4; ++m) {
#pragma unroll
    for (int n = 0; n < 4; ++n) {
      const int colL = n0 + wc * 64 + n * 16 + l15;
      const int jg = n_base + colL;
#pragma unroll
      for (int j = 0; j < 4; ++j) {
        const int row = m0 + wr * 64 + m * 16 + grp * 4 + j;
        float g = accg[m][n][j];
        float u = accu[m][n][j];
        unsigned int cw = cnt[(size_t)row * (D_FFN / 8) + (jg >> 3)];
        float c = (float)((cw >> ((jg & 7) * 4)) & 15u);
        float z = c * u * (g / (1.0f + __expf(-g)));
        Z[(size_t)row * NHALF + colL] = (bf16_t)z;
      }
    }
  }
}

// ---------------- GEMM2: down, 8-phase 256x128 clone (single acc) ----------
// 8 waves (4M x 2N), per-wave 64x64; acc = 64 VGPR. LDS 96K: 2 x {A 32K|B 16K}.
// 2 phases per K-tile (k0/k1); all 6 next-tile loads issue in P1.
#define BM2 256
#define BN2 128
#define BK2 64
#define NT2 (NHALF / BK2)     // 32 K-tiles
#define LDSBUF2 49152

__global__ __launch_bounds__(512, 2) void gemm_down_8p(
    const bf16_t* __restrict__ A,    // Z [N_TOK][NHALF]
    const bf16_t* __restrict__ B,    // [D_MODEL][D_FFN]  (w_down^T)
    float* __restrict__ C,           // [N_TOK][D_MODEL]
    int k_base, int accum)
{
  extern __shared__ char smem[];
  const int t = threadIdx.x;
  const int lane = t & 63;
  const int w = t >> 6;
  const int wr = w >> 1;           // 0..3 (M)
  const int wc = w & 1;            // 0..1 (N)
  const int l15 = lane & 15;
  const int grp = lane >> 4;
  const int m0 = blockIdx.x * BM2;
  const int n0 = blockIdx.y * BN2;

  int offA[4], offB[2];
#pragma unroll
  for (int c = 0; c < 4; ++c) {
    const int s = c * 512 + w * 64 + lane;
    const int r = s >> 3, cb = (s & 7) ^ (r & 7);
    offA[c] = (m0 + r) * NHALF + cb * 8;
  }
#pragma unroll
  for (int c = 0; c < 2; ++c) {
    const int s = c * 512 + w * 64 + lane;
    const int r = s >> 3, cb = (s & 7) ^ (r & 7);
    offB[c] = (n0 + r) * D_FFN + k_base + cb * 8;
  }
  const int dst0 = (w * 64 + lane) * 16;

  const int swz = l15 & 7;
  const int a_k0 = wr * 8192 + l15 * 128 + ((0 + grp) ^ swz) * 16;
  const int a_k1 = wr * 8192 + l15 * 128 + ((4 + grp) ^ swz) * 16;
  const int b_k0 = 32768 + wc * 8192 + l15 * 128 + ((0 + grp) ^ swz) * 16;
  const int b_k1 = 32768 + wc * 8192 + l15 * 128 + ((4 + grp) ^ swz) * 16;

  // prologue: tile 0 -> buf 0
#pragma unroll
  for (int c = 0; c < 4; ++c) gload_lds16(A + offA[c], smem + dst0 + c * 8192);
#pragma unroll
  for (int c = 0; c < 2; ++c) gload_lds16(B + offB[c], smem + 32768 + dst0 + c * 8192);
  asm volatile("s_waitcnt vmcnt(0)" ::: "memory");
  __builtin_amdgcn_s_barrier();

  f32x4 acc[4][4] = {};

  for (int tt = 0; tt < NT2; ++tt) {
    char* rb = smem + (tt & 1) * LDSBUF2;
    char* wb = smem + ((tt & 1) ^ 1) * LDSBUF2;
    const int kg = (tt + 1) * BK2;
    const bool st = (tt + 1 < NT2);
    bf16x8 af[4], bf[4];

    // ---- P1: k0 (+ all next-tile staging) ----
#pragma unroll
    for (int m = 0; m < 4; ++m) af[m] = *(const bf16x8*)(rb + a_k0 + m * 2048);
#pragma unroll
    for (int n = 0; n < 4; ++n) bf[n] = *(const bf16x8*)(rb + b_k0 + n * 2048);
    if (st) {
#pragma unroll
      for (int c = 0; c < 4; ++c) gload_lds16(A + offA[c] + kg, wb + dst0 + c * 8192);
#pragma unroll
      for (int c = 0; c < 2; ++c) gload_lds16(B + offB[c] + kg, wb + 32768 + dst0 + c * 8192);
    }
    PHASE_SYNC_PRE();
    MFMA16(acc, af, bf);
    PHASE_SYNC_POST();

    // ---- P2: k1 ----
#pragma unroll
    for (int m = 0; m < 4; ++m) af[m] = *(const bf16x8*)(rb + a_k1 + m * 2048);
#pragma unroll
    for (int n = 0; n < 4; ++n) bf[n] = *(const bf16x8*)(rb + b_k1 + n * 2048);
    __builtin_amdgcn_s_barrier();
    asm volatile("s_waitcnt lgkmcnt(0)" ::: "memory");
    __builtin_amdgcn_sched_barrier(0);
    __builtin_amdgcn_s_setprio(1);
    MFMA16(acc, af, bf);
    __builtin_amdgcn_s_setprio(0);
    if (st) asm volatile("s_waitcnt vmcnt(0)" ::: "memory");
    __builtin_amdgcn_s_barrier();
  }

  // epilogue
#pragma unroll
  for (int m = 0; m < 4; ++m) {
#pragma unroll
    for (int n = 0; n < 4; ++n) {
      const int col = n0 + wc * 64 + n * 16 + l15;
#pragma unroll
      for (int j = 0; j < 4; ++j) {
        const int row = m0 + wr * 64 + m * 16 + grp * 4 + j;
        const size_t off = (size_t)row * D_MODEL + col;
        float prev = accum ? C[off] : 0.0f;
        C[off] = prev + acc[m][n][j];
      }
    }
  }
}

// ---------------- launch ----------------

extern "C" void kernel_launch(void* const* d_in, const int* in_sizes, int n_in,
                              void* d_out, int out_size, void* d_ws, size_t ws_size,
                              hipStream_t stream) {
  const float* x  = (const float*)d_in[0];
  const int*   idx = (const int*)d_in[1];
  const float* wg = (const float*)d_in[2];
  const float* wu = (const float*)d_in[3];
  const float* wd = (const float*)d_in[4];
  float* out = (float*)d_out;

  char* ws = (char*)d_ws;
  const size_t SZ_XB  = (size_t)N_TOK * D_MODEL * 2;   // 16 MB
  const size_t SZ_W   = (size_t)D_MODEL * D_FFN * 2;   //  8 MB each
  const size_t SZ_CNT = (size_t)N_TOK * D_FFN / 2;     // 16 MB
  bf16_t* xb  = (bf16_t*)(ws);
  bf16_t* wgT = (bf16_t*)(ws + SZ_XB);
  bf16_t* wuT = (bf16_t*)(ws + SZ_XB + SZ_W);
  bf16_t* wdT = (bf16_t*)(ws + SZ_XB + 2 * SZ_W);
  unsigned int* cnt = (unsigned int*)(ws + SZ_XB + 3 * SZ_W);
  bf16_t* Z   = (bf16_t*)(ws + SZ_XB + 3 * SZ_W + SZ_CNT);  // [N_TOK][NHALF]
  // total ws use: 16 + 24 + 16 + 32 = 88 MB

  (void)hipFuncSetAttribute((const void*)gemm_gateup_8p,
                            hipFuncAttributeMaxDynamicSharedMemorySize, 131072);
  (void)hipFuncSetAttribute((const void*)gemm_down_8p,
                            hipFuncAttributeMaxDynamicSharedMemorySize, 98304);

  count_scatter_lds<<<N_TOK / ROWS_PER_BLK, 256, 0, stream>>>(idx, cnt);
  cvt_f32_bf16<<<(N_TOK * D_MODEL / 4 + 255) / 256, 256, 0, stream>>>(x, xb, N_TOK * D_MODEL / 4);
  transpose_cvt<<<dim3(D_FFN / 32, D_MODEL / 32), dim3(32, 8), 0, stream>>>(wg, wgT, D_MODEL, D_FFN);
  transpose_cvt<<<dim3(D_FFN / 32, D_MODEL / 32), dim3(32, 8), 0, stream>>>(wu, wuT, D_MODEL, D_FFN);
  transpose_cvt<<<dim3(D_MODEL / 32, D_FFN / 32), dim3(32, 8), 0, stream>>>(wd, wdT, D_FFN, D_MODEL);

  // two FFN halves, Z buffer reused (stream-ordered)
  gemm_gateup_8p<<<dim3(N_TOK / BM1, NHALF / BN1), 512, 131072, stream>>>(xb, wgT, wuT, cnt, Z, 0);
  gemm_down_8p<<<dim3(N_TOK / BM2, D_MODEL / BN2), 512, 98304, stream>>>(Z, wdT, out, 0, 0);
  gemm_gateup_8p<<<dim3(N_TOK / BM1, NHALF / BN1), 512, 131072, stream>>>(xb, wgT, wuT, cnt, Z, NHALF);
  gemm_down_8p<<<dim3(N_TOK / BM2, D_MODEL / BN2), 512, 98304, stream>>>(Z, wdT, out, NHALF, 1);
}